// Round 16
// baseline (356.035 us; speedup 1.0000x reference)
//
#include <hip/hip_runtime.h>
#include <stdint.h>

#define N_ 8192
#define M_ 4096
#define FIN_ 256
#define F_ 128
#define B_ 2048

typedef __attribute__((ext_vector_type(8))) short vs8;
typedef __attribute__((ext_vector_type(8))) __bf16 vb8;
typedef __attribute__((ext_vector_type(4))) float vf4;

union ABu { vs8 s; vb8 b; };

__device__ __forceinline__ vf4 mfma16(const ABu& a, const ABu& b, vf4 c) {
    return __builtin_amdgcn_mfma_f32_16x16x32_bf16(a.b, b.b, c, 0, 0, 0);
}
__device__ __forceinline__ unsigned short f2b(float x) {
    union { float f; unsigned u; } v; v.f = x;
    unsigned r = v.u + 0x7fffu + ((v.u >> 16) & 1u);
    return (unsigned short)(r >> 16);
}
__device__ __forceinline__ float lrelu(float x) { return x > 0.f ? x : 0.2f * x; }

// async global->LDS, 16B per lane; per-lane global src, wave-uniform LDS base (HW adds lane*16)
__device__ __forceinline__ void glds16(const unsigned short* g, void* l) {
    __builtin_amdgcn_global_load_lds((const __attribute__((address_space(1))) unsigned int*)g,
                                     (__attribute__((address_space(3))) unsigned int*)l, 16, 0, 0);
}

// ---- prep: W[256][128] f32 -> WT[128][256] bf16  +  zero stats (2KB only) ----
__global__ void k_prep(const float* __restrict__ W1, const float* __restrict__ W2,
                       unsigned short* __restrict__ W1T, unsigned short* __restrict__ W2T,
                       float4* __restrict__ Z, int nz4) {
    int id = blockIdx.x * 256 + threadIdx.x;
    if (id < 65536) {
        const float* W = (id < 32768) ? W1 : W2;
        unsigned short* WT = (id < 32768) ? W1T : W2T;
        int o = id & 32767;
        int f = o >> 8, k = o & 255;
        WT[o] = f2b(W[k * F_ + f]);
    } else {
        int z = id - 65536;
        if (z < nz4) Z[z] = make_float4(0.f, 0.f, 0.f, 0.f);
    }
}

// ---- FUSED: h = X@W (MFMA); write h2 f32, packed hP[kblk][f][32] bf16, s1/s2 row-dots ----
__global__ __launch_bounds__(256) void k_hgemmF(const float* __restrict__ Rin, const float* __restrict__ Sin,
                                                const unsigned short* __restrict__ W1T,
                                                const unsigned short* __restrict__ W2T,
                                                const float* __restrict__ a,
                                                float* __restrict__ h2,
                                                unsigned short* __restrict__ h1P, unsigned short* __restrict__ h2P,
                                                float* __restrict__ s1, float* __restrict__ s2) {
    __shared__ unsigned short tb[16][136];               // 16 rows x 128 f, padded
    __shared__ float sred[4][16];
    int t = threadIdx.x;
    int w = t >> 6, l = t & 63, lr = l & 15, lg = l >> 4;
    int gr = blockIdx.x * 16;
    const float* X; const unsigned short* WT; unsigned short* HP; float* sout; const float* av;
    int row0; bool isH2;
    if (gr < M_) { X = Rin; WT = W1T; HP = h1P; sout = s1; av = a;      row0 = gr;      isH2 = false; }
    else         { X = Sin; WT = W2T; HP = h2P; sout = s2; av = a + F_; row0 = gr - M_; isH2 = true;  }
    int fbase = w * 32;
    vf4 acc[2] = {};
    const float* xp = X + (size_t)(row0 + lr) * FIN_ + lg * 8;
#pragma unroll
    for (int kk = 0; kk < FIN_; kk += 32) {
        float4 xa = *(const float4*)(xp + kk);
        float4 xb = *(const float4*)(xp + kk + 4);
        ABu af;
        af.s[0] = (short)f2b(xa.x); af.s[1] = (short)f2b(xa.y);
        af.s[2] = (short)f2b(xa.z); af.s[3] = (short)f2b(xa.w);
        af.s[4] = (short)f2b(xb.x); af.s[5] = (short)f2b(xb.y);
        af.s[6] = (short)f2b(xb.z); af.s[7] = (short)f2b(xb.w);
#pragma unroll
        for (int q = 0; q < 2; ++q) {
            ABu bf; bf.s = *(const vs8*)(WT + (fbase + q * 16 + lr) * FIN_ + kk + lg * 8);
            acc[q] = mfma16(af, bf, acc[q]);
        }
    }
    if (isH2) {
#pragma unroll
        for (int q = 0; q < 2; ++q)
#pragma unroll
            for (int r = 0; r < 4; ++r)
                h2[(size_t)(row0 + lg * 4 + r) * F_ + fbase + q * 16 + lr] = acc[q][r];
    }
#pragma unroll
    for (int q = 0; q < 2; ++q)
#pragma unroll
        for (int r = 0; r < 4; ++r)
            tb[lg * 4 + r][fbase + q * 16 + lr] = f2b(acc[q][r]);
    float a0 = av[fbase + lr], a1 = av[fbase + 16 + lr];
    float tv[4];
#pragma unroll
    for (int r = 0; r < 4; ++r) tv[r] = acc[0][r] * a0 + acc[1][r] * a1;
#pragma unroll
    for (int off = 1; off < 16; off <<= 1)
#pragma unroll
        for (int r = 0; r < 4; ++r) tv[r] += __shfl_xor(tv[r], off, 64);
    if ((l & 15) == 0)
#pragma unroll
        for (int r = 0; r < 4; ++r) sred[w][lg * 4 + r] = tv[r];
    __syncthreads();
    {
        int f = t >> 1, half = t & 1;
        vs8 o;
#pragma unroll
        for (int j = 0; j < 8; ++j) o[j] = (short)tb[half * 8 + j][f];
        *(vs8*)(HP + ((size_t)(row0 >> 5) * 128 + f) * 32 + (row0 & 16) + half * 8) = o;
    }
    if (t < 16) {
        float s = sred[0][t] + sred[1][t] + sred[2][t] + sred[3][t];
        sout[row0 + t] = s;
    }
}

// ---- FUSED: inter stats+bitmask | city/prov bitmask+counts | h2wP gather ----
__global__ __launch_bounds__(256) void k_adjgather(const int* __restrict__ inter, const float* __restrict__ s1,
                                                   const float* __restrict__ s2, unsigned short* __restrict__ bm,
                                                   float* __restrict__ rowmax, float* __restrict__ rowinv,
                                                   const int* __restrict__ city, const int* __restrict__ prov,
                                                   const int* __restrict__ src,
                                                   uint32_t* __restrict__ BMtc, uint32_t* __restrict__ BMtp,
                                                   float* __restrict__ w3, float* __restrict__ w4,
                                                   const float* __restrict__ h2, unsigned short* __restrict__ h2wP) {
    __shared__ float wred[8];
    int t = threadIdx.x;
    int wv = t >> 6, ln = t & 63;
    if (blockIdx.x < N_) {
        int n = blockIdx.x;
        const int* rp = inter + (size_t)n * M_ + t * 16;
        float sv[16]; unsigned mask = 0;
#pragma unroll
        for (int c = 0; c < 4; ++c) {
            int4 v = *(const int4*)(rp + c * 4);
            if (v.x > 0) mask |= 1u << (c * 4 + 0);
            if (v.y > 0) mask |= 1u << (c * 4 + 1);
            if (v.z > 0) mask |= 1u << (c * 4 + 2);
            if (v.w > 0) mask |= 1u << (c * 4 + 3);
            float4 s = *(const float4*)(s1 + t * 16 + c * 4);
            sv[c * 4 + 0] = s.x; sv[c * 4 + 1] = s.y; sv[c * 4 + 2] = s.z; sv[c * 4 + 3] = s.w;
        }
        bm[(size_t)n * 256 + t] = (unsigned short)(mask & 0xffffu);
        float mx = -3.0e38f;
#pragma unroll
        for (int j = 0; j < 16; ++j) if (mask & (1u << j)) mx = fmaxf(mx, sv[j]);
        for (int off = 32; off > 0; off >>= 1) mx = fmaxf(mx, __shfl_down(mx, off, 64));
        if (ln == 0) wred[wv] = mx;
        __syncthreads();
        float s1mx = fmaxf(fmaxf(wred[0], wred[1]), fmaxf(wred[2], wred[3]));
        float s2n = s2[n];
        float rmx = lrelu(s2n + s1mx);
        float sum = 0.f;
#pragma unroll
        for (int j = 0; j < 16; ++j) if (mask & (1u << j)) sum += __expf(lrelu(s2n + sv[j]) - rmx);
        for (int off = 32; off > 0; off >>= 1) sum += __shfl_down(sum, off, 64);
        if (ln == 0) wred[4 + wv] = sum;
        __syncthreads();
        if (t == 0) {
            float tot = wred[4] + wred[5] + wred[6] + wred[7];
            bool any = s1mx > -2.9e38f;
            rowmax[n] = any ? rmx : 0.f;
            rowinv[n] = (any && tot > 0.f) ? 1.0f / tot : 0.f;
        }
    } else if (blockIdx.x < N_ + 2 * B_) {
        int bb = blockIdx.x - N_;
        int b = bb & (B_ - 1);
        bool isC = bb < B_;
        const int* adj = isC ? city : prov;
        uint32_t* BM = isC ? BMtc : BMtp;
        float* wout = isC ? w3 : w4;
        const int* rowp = adj + (size_t)src[b] * N_;
        int cnt = 0;
#pragma unroll 4
        for (int i = 0; i < N_ / 256; ++i) {
            int v = rowp[i * 256 + t];
            unsigned long long bal = __ballot(v > 0);
            cnt += (v > 0);
            if (ln == 0) {
                int widx = i * 8 + wv * 2;
                BM[(size_t)widx * B_ + b] = (uint32_t)bal;
                BM[(size_t)(widx + 1) * B_ + b] = (uint32_t)(bal >> 32);
            }
        }
        float fc = (float)cnt;
        for (int off = 32; off > 0; off >>= 1) fc += __shfl_down(fc, off, 64);
        if (ln == 0) wred[wv] = fc;
        __syncthreads();
        if (t == 0) {
            float tot = wred[0] + wred[1] + wred[2] + wred[3];
            wout[b] = tot > 0.f ? 1.0f / tot : 0.f;
        }
    } else {
        int bblk = blockIdx.x - (N_ + 2 * B_);            // 64 blocks
        int f = t & 127, halfb = t >> 7;
        vs8 o0, o1;
#pragma unroll
        for (int i = 0; i < 8; ++i) {
            int b0 = bblk * 32 + halfb * 16 + i;
            o0[i] = (short)f2b(h2[(size_t)src[b0] * F_ + f]);
            int b1 = b0 + 8;
            o1[i] = (short)f2b(h2[(size_t)src[b1] * F_ + f]);
        }
        unsigned short* dst = h2wP + ((size_t)bblk * 128 + f) * 32 + halfb * 16;
        *(vs8*)dst = o0;
        *(vs8*)(dst + 8) = o1;
    }
}

// ---- ballot bit-transpose: bm[n][m-bits] -> bmT[m][n-bits], 64x64-bit tiles (R5-verified) ----
__global__ __launch_bounds__(256) void k_bitT(const unsigned long long* __restrict__ bm64,
                                              unsigned long long* __restrict__ bmT64) {
    int tile = blockIdx.x * 4 + (threadIdx.x >> 6);       // 8192 tiles: 128 n-tiles x 64 m-tiles
    int l = threadIdx.x & 63;
    int tn = tile >> 6, tm = tile & 63;
    unsigned long long row = bm64[(size_t)(tn * 64 + l) * 64 + tm];
    unsigned long long mine = 0;
#pragma unroll
    for (int c = 0; c < 64; ++c) {
        unsigned long long b = __ballot((unsigned)((row >> c) & 1ull));
        if (l == c) mine = b;
    }
    bmT64[(size_t)(tm * 64 + l) * 128 + tn] = mine;
}

// ---- MERGED gemmA | gemmB (pipelined: regen-att->LDS producer + glds16 B) | gemmC ----
__global__ __launch_bounds__(256) void k_gemmABC(const uint32_t* __restrict__ bm32,
                                                 const uint32_t* __restrict__ bmT32,
                                                 const float* __restrict__ s1, const float* __restrict__ s2,
                                                 const float* __restrict__ rowmax, const float* __restrict__ rowinv,
                                                 const unsigned short* __restrict__ h1P,
                                                 const unsigned short* __restrict__ h2P,
                                                 const uint32_t* __restrict__ BMtc, const uint32_t* __restrict__ BMtp,
                                                 const float* __restrict__ w3, const float* __restrict__ w4,
                                                 const unsigned short* __restrict__ h2wP,
                                                 float* __restrict__ uP, float* __restrict__ vP) {
    __shared__ __align__(16) unsigned short ldsA[2][4096];   // [buf][128 rows x 32 k]
    __shared__ __align__(16) unsigned short ldsB[2][4096];   // [buf][128 f x 32 k]
    int t = threadIdx.x;
    int w = t >> 6, l = t & 63;
    int lr = l & 15, lg = l >> 4;
    int bx = blockIdx.x;
    if (bx < 384) {
        // gemmA (bx<256): uP[y] = att @ h1 (64 x-tiles x 4 y, 32 steps)
        // gemmB (256..383): vP[y] = att.T @ h2 (32 x-tiles x 4 y, 64 steps)
        bool isA = bx < 256;
        int i = isA ? bx : bx - 256;
        int x, y, ns, kbase;
        const unsigned short* Bsrc; float* Out;
        if (isA) { x = i & 63; y = i >> 6; ns = 32; kbase = y * 32;
                   Bsrc = h1P; Out = uP + (size_t)y * N_ * F_; }
        else     { x = i & 31; y = i >> 5; ns = 64; kbase = y * 64;
                   Bsrc = h2P; Out = vP + (size_t)y * M_ * F_; }
        int rb0 = x * 128;
        int rq = (w >> 1) * 64;                          // wave row-quadrant
        int cb = (w & 1) * 64;                           // wave col-half
        int rrow = t >> 2, oct = t & 3;                  // regen: row 0..63 (x2), k-octet 0..3
        auto regen = [&](int kb, int buf) {
            unsigned short* dst = ldsA[buf] + rrow * 32 + oct * 8;
            if (isA) {
                float4 sa = *(const float4*)(s1 + kb * 32 + oct * 8);
                float4 sb = *(const float4*)(s1 + kb * 32 + oct * 8 + 4);
                float sv[8] = {sa.x, sa.y, sa.z, sa.w, sb.x, sb.y, sb.z, sb.w};
#pragma unroll
                for (int uu = 0; uu < 2; ++uu) {
                    int n = rb0 + rrow + uu * 64;
                    uint32_t bits = bm32[(size_t)n * 128 + kb] >> (oct * 8);
                    float s2n = s2[n], rmx = rowmax[n], rin = rowinv[n];
                    vs8 o;
#pragma unroll
                    for (int j = 0; j < 8; ++j) {
                        float v = ((bits >> j) & 1u) ? __expf(lrelu(s2n + sv[j]) - rmx) * rin : 0.f;
                        o[j] = (short)f2b(v);
                    }
                    *(vs8*)(dst + uu * 2048) = o;
                }
            } else {
                float4 za = *(const float4*)(s2 + kb * 32 + oct * 8);
                float4 zb = *(const float4*)(s2 + kb * 32 + oct * 8 + 4);
                float4 ra = *(const float4*)(rowmax + kb * 32 + oct * 8);
                float4 rb2 = *(const float4*)(rowmax + kb * 32 + oct * 8 + 4);
                float4 ia = *(const float4*)(rowinv + kb * 32 + oct * 8);
                float4 ib = *(const float4*)(rowinv + kb * 32 + oct * 8 + 4);
                float zv[8] = {za.x, za.y, za.z, za.w, zb.x, zb.y, zb.z, zb.w};
                float rv[8] = {ra.x, ra.y, ra.z, ra.w, rb2.x, rb2.y, rb2.z, rb2.w};
                float iv[8] = {ia.x, ia.y, ia.z, ia.w, ib.x, ib.y, ib.z, ib.w};
#pragma unroll
                for (int uu = 0; uu < 2; ++uu) {
                    int m = rb0 + rrow + uu * 64;
                    uint32_t bits = bmT32[(size_t)m * 256 + kb] >> (oct * 8);
                    float s1m = s1[m];
                    vs8 o;
#pragma unroll
                    for (int j = 0; j < 8; ++j) {
                        float v = ((bits >> j) & 1u) ? __expf(lrelu(zv[j] + s1m) - rv[j]) * iv[j] : 0.f;
                        o[j] = (short)f2b(v);
                    }
                    *(vs8*)(dst + uu * 2048) = o;
                }
            }
        };
        auto stageB = [&](int kb, int buf) {
#pragma unroll
            for (int ii = 0; ii < 2; ++ii) {
                int c = w * 2 + ii;                      // 8 chunks of 1KB
                glds16(Bsrc + (size_t)kb * 4096 + c * 512 + l * 8, ldsB[buf] + c * 512);
            }
        };
        vf4 acc[4][4] = {};
        regen(kbase, 0);
        stageB(kbase, 0);
        __syncthreads();
        int cur = 0;
        for (int step = 0; step < ns; ++step) {
            int kb = kbase + step;
            if (step + 1 < ns) stageB(kb + 1, cur ^ 1);  // issue long-latency loads early
            ABu a[4], b[4];
#pragma unroll
            for (int s = 0; s < 4; ++s) a[s].s = *(const vs8*)(ldsA[cur] + (rq + s * 16 + lr) * 32 + lg * 8);
#pragma unroll
            for (int q = 0; q < 4; ++q) b[q].s = *(const vs8*)(ldsB[cur] + (cb + q * 16 + lr) * 32 + lg * 8);
#pragma unroll
            for (int s = 0; s < 4; ++s)
#pragma unroll
                for (int q = 0; q < 4; ++q) acc[s][q] = mfma16(a[s], b[q], acc[s][q]);
            if (step + 1 < ns) regen(kb + 1, cur ^ 1);   // VALU overlaps MFMA drain
            __syncthreads();                             // drains ds_write + vmcnt + reads
            cur ^= 1;
        }
#pragma unroll
        for (int s = 0; s < 4; ++s)
#pragma unroll
            for (int q = 0; q < 4; ++q)
#pragma unroll
                for (int r = 0; r < 4; ++r)
                    Out[(size_t)(rb0 + rq + s * 16 + lg * 4 + r) * F_ + cb + q * 16 + lr] = acc[s][q][r];
    } else {
        // ---- gemmC: uP[4+y] = G @ h2w K-slice (128 x-tiles x 2 y) ----
        int i = bx - 384;
        int xc = i & 127, yc = i >> 7;
        int nb0 = xc * 64 + (w & 1) * 32;                // 32-aligned -> wi uniform per wave
        int fb = (w >> 1) * 64;
        int wi = nb0 >> 5;
        const uint32_t* bc = BMtc + (size_t)wi * B_;
        const uint32_t* bp = BMtp + (size_t)wi * B_;
        vf4 acc[2][4] = {};
        int b0s = yc * (B_ / 2);
        for (int b0 = b0s; b0 < b0s + B_ / 2; b0 += 32) {
            int bb = b0 + lg * 8;
            uint4 c0 = *(const uint4*)(bc + bb);
            uint4 c1 = *(const uint4*)(bc + bb + 4);
            uint4 p0 = *(const uint4*)(bp + bb);
            uint4 p1 = *(const uint4*)(bp + bb + 4);
            float4 wa = *(const float4*)(w3 + bb);
            float4 wb = *(const float4*)(w3 + bb + 4);
            float4 wc = *(const float4*)(w4 + bb);
            float4 wd = *(const float4*)(w4 + bb + 4);
            const unsigned short* hb = h2wP + (size_t)(b0 >> 5) * 128 * 32;
            ABu bf0, bf1, bf2, bf3;
            bf0.s = *(const vs8*)(hb + (size_t)(fb + lr) * 32 + lg * 8);
            bf1.s = *(const vs8*)(hb + (size_t)(fb + 16 + lr) * 32 + lg * 8);
            bf2.s = *(const vs8*)(hb + (size_t)(fb + 32 + lr) * 32 + lg * 8);
            bf3.s = *(const vs8*)(hb + (size_t)(fb + 48 + lr) * 32 + lg * 8);
            uint32_t cw[8] = {c0.x, c0.y, c0.z, c0.w, c1.x, c1.y, c1.z, c1.w};
            uint32_t pw[8] = {p0.x, p0.y, p0.z, p0.w, p1.x, p1.y, p1.z, p1.w};
            float w3v[8] = {wa.x, wa.y, wa.z, wa.w, wb.x, wb.y, wb.z, wb.w};
            float w4v[8] = {wc.x, wc.y, wc.z, wc.w, wd.x, wd.y, wd.z, wd.w};
            ABu af0, af1;
#pragma unroll
            for (int j = 0; j < 8; ++j) {
                float v0 = (((cw[j] >> lr) & 1u) ? w3v[j] : 0.f) + (((pw[j] >> lr) & 1u) ? w4v[j] : 0.f);
                float v1 = (((cw[j] >> (16 + lr)) & 1u) ? w3v[j] : 0.f) + (((pw[j] >> (16 + lr)) & 1u) ? w4v[j] : 0.f);
                af0.s[j] = (short)f2b(v0);
                af1.s[j] = (short)f2b(v1);
            }
            acc[0][0] = mfma16(af0, bf0, acc[0][0]);
            acc[1][0] = mfma16(af1, bf0, acc[1][0]);
            acc[0][1] = mfma16(af0, bf1, acc[0][1]);
            acc[1][1] = mfma16(af1, bf1, acc[1][1]);
            acc[0][2] = mfma16(af0, bf2, acc[0][2]);
            acc[1][2] = mfma16(af1, bf2, acc[1][2]);
            acc[0][3] = mfma16(af0, bf3, acc[0][3]);
            acc[1][3] = mfma16(af1, bf3, acc[1][3]);
        }
        float* Out = uP + (size_t)(4 + yc) * N_ * F_;
#pragma unroll
        for (int s = 0; s < 2; ++s)
#pragma unroll
            for (int q = 0; q < 4; ++q)
#pragma unroll
                for (int r = 0; r < 4; ++r)
                    Out[(size_t)(nb0 + s * 16 + lg * 4 + r) * F_ + fb + q * 16 + lr] = acc[s][q][r];
    }
}

// ---- batchnorm column stats straight from partial slabs ----
__global__ __launch_bounds__(256) void k_bnstats3(const float* __restrict__ vP, const float* __restrict__ uP,
                                                  float* __restrict__ stats) {
    __shared__ float r1[256], r2[256];
    int bx = blockIdx.x;
    int f = threadIdx.x & 127;
    int half = threadIdx.x >> 7;
    float s = 0.f, s2v = 0.f;
    if (bx < 256) {
        size_t stride = (size_t)M_ * F_;
        for (int r = bx * 2 + half; r < M_; r += 512) {
            float v = 0.f;
#pragma unroll
            for (int y = 0; y < 4; ++y) v += vP[(size_t)y * stride + (size_t)r * F_ + f];
            s += v; s2v += v * v;
        }
        r1[threadIdx.x] = s; r2[threadIdx.x] = s2v;
        __syncthreads();
        if (half == 0) {
            atomicAdd(&stats[f], r1[f] + r1[f + 128]);
            atomicAdd(&stats[128 + f], r2[f] + r2[f + 128]);
        }
    } else {
        int b = bx - 256;
        size_t stride = (size_t)N_ * F_;
        for (int r = b * 2 + half; r < N_; r += 512) {
            float v = 0.f;
#pragma unroll
            for (int y = 0; y < 6; ++y) v += uP[(size_t)y * stride + (size_t)r * F_ + f];
            s += v; s2v += v * v;
        }
        r1[threadIdx.x] = s; r2[threadIdx.x] = s2v;
        __syncthreads();
        if (half == 0) {
            atomicAdd(&stats[256 + f], r1[f] + r1[f + 128]);
            atomicAdd(&stats[384 + f], r2[f] + r2[f + 128]);
        }
    }
}

// ---- bn finalize + sum partials in-register + apply + leaky + cast bf16 ----
__global__ __launch_bounds__(256) void k_bnapplyP(const float* __restrict__ vP, const float* __restrict__ uP,
                                                  const float* __restrict__ stats,
                                                  const float* __restrict__ g1, const float* __restrict__ b1,
                                                  const float* __restrict__ g2, const float* __restrict__ b2,
                                                  unsigned short* __restrict__ v_outb, unsigned short* __restrict__ u_outb) {
    __shared__ float sc[256], sh[256];                    // [which*128+f]
    int t = threadIdx.x;
    {
        int which = t >> 7, f = t & 127;
        const float* sum = stats + which * 256;
        const float* sq = sum + 128;
        const float* g = which ? g2 : g1;
        const float* be = which ? b2 : b1;
        float R = which ? (float)N_ : (float)M_;
        float mean = sum[f] / R;
        float var = sq[f] / R - mean * mean;
        float s = g[f] * rsqrtf(var + 1e-5f);
        sc[t] = s; sh[t] = be[f] - mean * s;
    }
    __syncthreads();
    int id4 = blockIdx.x * 256 + t;                       // one float4 per thread
    int idx = id4 * 4;
    int which = idx >= M_ * F_;
    int rel = which ? idx - M_ * F_ : idx;
    int f0 = (rel & 127) + which * 128;
    float4 p = make_float4(0.f, 0.f, 0.f, 0.f);
    unsigned short* Q;
    if (!which) {
        size_t stride = (size_t)M_ * F_;
#pragma unroll
        for (int y = 0; y < 4; ++y) {
            float4 q = *(const float4*)(vP + (size_t)y * stride + rel);
            p.x += q.x; p.y += q.y; p.z += q.z; p.w += q.w;
        }
        Q = v_outb;
    } else {
        size_t stride = (size_t)N_ * F_;
#pragma unroll
        for (int y = 0; y < 6; ++y) {
            float4 q = *(const float4*)(uP + (size_t)y * stride + rel);
            p.x += q.x; p.y += q.y; p.z += q.z; p.w += q.w;
        }
        Q = u_outb;
    }
    ushort4 o;
    o.x = f2b(lrelu(p.x * sc[f0 + 0] + sh[f0 + 0]));
    o.y = f2b(lrelu(p.y * sc[f0 + 1] + sh[f0 + 1]));
    o.z = f2b(lrelu(p.z * sc[f0 + 2] + sh[f0 + 2]));
    o.w = f2b(lrelu(p.w * sc[f0 + 3] + sh[f0 + 3]));
    *(ushort4*)(Q + rel) = o;
}

// ---------------- out = elu(U @ V^T) ----------------
__global__ __launch_bounds__(256) void k_gemmD(const unsigned short* __restrict__ U,
                                               const unsigned short* __restrict__ V,
                                               float* __restrict__ out) {
    int w = threadIdx.x >> 6, l = threadIdx.x & 63;
    int lr = l & 15, lg = l >> 4;
    int nb = blockIdx.x * 64 + w * 16;
    int mb = blockIdx.y * 64;
    vf4 acc[4] = {};
#pragma unroll
    for (int k0 = 0; k0 < F_; k0 += 32) {
        ABu af; af.s = *(const vs8*)(U + (size_t)(nb + lr) * F_ + k0 + lg * 8);
#pragma unroll
        for (int q = 0; q < 4; ++q) {
            ABu bf; bf.s = *(const vs8*)(V + (size_t)(mb + q * 16 + lr) * F_ + k0 + lg * 8);
            acc[q] = mfma16(af, bf, acc[q]);
        }
    }
#pragma unroll
    for (int q = 0; q < 4; ++q)
#pragma unroll
        for (int r = 0; r < 4; ++r) {
            int row = nb + lg * 4 + r;
            int col = mb + q * 16 + lr;
            float x = acc[q][r];
            out[(size_t)row * M_ + col] = x > 0.f ? x : __expf(x) - 1.f;
        }
}

extern "C" void kernel_launch(void* const* d_in, const int* in_sizes, int n_in,
                              void* d_out, int out_size, void* d_ws, size_t ws_size,
                              hipStream_t stream) {
    const float* Sinput = (const float*)d_in[0];
    const float* Rinput = (const float*)d_in[1];
    const int* inter_adj = (const int*)d_in[2];
    const int* city_adj = (const int*)d_in[3];
    const int* prov_adj = (const int*)d_in[4];
    const int* src = (const int*)d_in[5];
    const float* W1 = (const float*)d_in[6];
    const float* W2 = (const float*)d_in[7];
    const float* a = (const float*)d_in[8];
    const float* g1 = (const float*)d_in[11];
    const float* b1 = (const float*)d_in[12];
    const float* g2 = (const float*)d_in[13];
    const float* b2 = (const float*)d_in[14];
    float* out = (float*)d_out;

    char* ws = (char*)d_ws;
    size_t o = 0;
    auto take = [&](size_t bytes) { char* p = ws + o; o += (bytes + 255) & ~(size_t)255; return p; };
    float* stats = (float*)take(512 * 4);
    size_t zero_bytes = o;                               // ONLY stats zeroed
    float* uP = (float*)take((size_t)6 * N_ * F_ * 4);   // 24 MB: gemmA y0..3 + gemmC y4..5
    float* vP = (float*)take((size_t)4 * M_ * F_ * 4);   // 8 MB: gemmB y0..3
    float* h2 = (float*)take((size_t)N_ * F_ * 4);
    unsigned short* h1P = (unsigned short*)take((size_t)(M_ / 32) * 128 * 32 * 2);
    unsigned short* h2P = (unsigned short*)take((size_t)(N_ / 32) * 128 * 32 * 2);
    unsigned short* W1T = (unsigned short*)take((size_t)F_ * FIN_ * 2);
    unsigned short* W2T = (unsigned short*)take((size_t)F_ * FIN_ * 2);
    float* s1 = (float*)take(M_ * 4);
    float* s2 = (float*)take(N_ * 4);
    float* rowmax = (float*)take(N_ * 4);
    float* rowinv = (float*)take(N_ * 4);
    float* w3 = (float*)take(B_ * 4);
    float* w4 = (float*)take(B_ * 4);
    unsigned short* h2wP = (unsigned short*)take((size_t)(B_ / 32) * 128 * 32 * 2);
    unsigned short* u_outb = (unsigned short*)take((size_t)N_ * F_ * 2);
    unsigned short* v_outb = (unsigned short*)take((size_t)M_ * F_ * 2);
    uint32_t* BMtc = (uint32_t*)take((size_t)256 * B_ * 4);
    uint32_t* BMtp = (uint32_t*)take((size_t)256 * B_ * 4);
    unsigned short* bm = (unsigned short*)take((size_t)N_ * 256 * 2);      // 4 MB, [n][m-bits]
    unsigned short* bmT = (unsigned short*)take((size_t)M_ * 512 * 2);     // 4 MB, [m][n-bits]
    (void)ws_size; (void)in_sizes; (void)n_in; (void)out_size;

    int nz4 = (int)(zero_bytes / 16);
    int zblocks = (nz4 + 255) / 256;
    k_prep<<<256 + zblocks, 256, 0, stream>>>(W1, W2, W1T, W2T, (float4*)d_ws, nz4);
    k_hgemmF<<<(M_ + N_) / 16, 256, 0, stream>>>(Rinput, Sinput, W1T, W2T, a, h2, h1P, h2P, s1, s2);
    k_adjgather<<<N_ + 2 * B_ + B_ / 32, 256, 0, stream>>>(inter_adj, s1, s2, bm, rowmax, rowinv,
                                                           city_adj, prov_adj, src, BMtc, BMtp, w3, w4,
                                                           h2, h2wP);
    k_bitT<<<2048, 256, 0, stream>>>((const unsigned long long*)bm, (unsigned long long*)bmT);
    k_gemmABC<<<640, 256, 0, stream>>>((const uint32_t*)bm, (const uint32_t*)bmT,
                                       s1, s2, rowmax, rowinv, h1P, h2P,
                                       BMtc, BMtp, w3, w4, h2wP, uP, vP);
    k_bnstats3<<<512, 256, 0, stream>>>(vP, uP, stats);
    k_bnapplyP<<<(M_ + N_) * F_ / 4 / 256, 256, 0, stream>>>(vP, uP, stats, g1, b1, g2, b2, v_outb, u_outb);
    k_gemmD<<<dim3(N_ / 64, M_ / 64), 256, 0, stream>>>(u_outb, v_outb, out);
}

// Round 17
// 322.281 us; speedup vs baseline: 1.1047x; 1.1047x over previous
//
#include <hip/hip_runtime.h>
#include <stdint.h>

#define N_ 8192
#define M_ 4096
#define FIN_ 256
#define F_ 128
#define B_ 2048

typedef __attribute__((ext_vector_type(8))) short vs8;
typedef __attribute__((ext_vector_type(8))) __bf16 vb8;
typedef __attribute__((ext_vector_type(4))) float vf4;

union ABu { vs8 s; vb8 b; };

__device__ __forceinline__ vf4 mfma16(const ABu& a, const ABu& b, vf4 c) {
    return __builtin_amdgcn_mfma_f32_16x16x32_bf16(a.b, b.b, c, 0, 0, 0);
}
__device__ __forceinline__ unsigned short f2b(float x) {
    union { float f; unsigned u; } v; v.f = x;
    unsigned r = v.u + 0x7fffu + ((v.u >> 16) & 1u);
    return (unsigned short)(r >> 16);
}
__device__ __forceinline__ float lrelu(float x) { return x > 0.f ? x : 0.2f * x; }

// async global->LDS, 16B per lane; per-lane global src, wave-uniform LDS base (HW adds lane*16)
__device__ __forceinline__ void glds16(const unsigned short* g, void* l) {
    __builtin_amdgcn_global_load_lds((const __attribute__((address_space(1))) unsigned int*)g,
                                     (__attribute__((address_space(3))) unsigned int*)l, 16, 0, 0);
}

// ---- prep: W[256][128] f32 -> WT[128][256] bf16  +  zero stats (2KB only) ----
__global__ void k_prep(const float* __restrict__ W1, const float* __restrict__ W2,
                       unsigned short* __restrict__ W1T, unsigned short* __restrict__ W2T,
                       float4* __restrict__ Z, int nz4) {
    int id = blockIdx.x * 256 + threadIdx.x;
    if (id < 65536) {
        const float* W = (id < 32768) ? W1 : W2;
        unsigned short* WT = (id < 32768) ? W1T : W2T;
        int o = id & 32767;
        int f = o >> 8, k = o & 255;
        WT[o] = f2b(W[k * F_ + f]);
    } else {
        int z = id - 65536;
        if (z < nz4) Z[z] = make_float4(0.f, 0.f, 0.f, 0.f);
    }
}

// ---- FUSED: h = X@W (MFMA); write h2 f32, packed hP[kblk][f][32] bf16, s1/s2 row-dots ----
__global__ __launch_bounds__(256) void k_hgemmF(const float* __restrict__ Rin, const float* __restrict__ Sin,
                                                const unsigned short* __restrict__ W1T,
                                                const unsigned short* __restrict__ W2T,
                                                const float* __restrict__ a,
                                                float* __restrict__ h2,
                                                unsigned short* __restrict__ h1P, unsigned short* __restrict__ h2P,
                                                float* __restrict__ s1, float* __restrict__ s2) {
    __shared__ unsigned short tb[16][136];               // 16 rows x 128 f, padded
    __shared__ float sred[4][16];
    int t = threadIdx.x;
    int w = t >> 6, l = t & 63, lr = l & 15, lg = l >> 4;
    int gr = blockIdx.x * 16;
    const float* X; const unsigned short* WT; unsigned short* HP; float* sout; const float* av;
    int row0; bool isH2;
    if (gr < M_) { X = Rin; WT = W1T; HP = h1P; sout = s1; av = a;      row0 = gr;      isH2 = false; }
    else         { X = Sin; WT = W2T; HP = h2P; sout = s2; av = a + F_; row0 = gr - M_; isH2 = true;  }
    int fbase = w * 32;
    vf4 acc[2] = {};
    const float* xp = X + (size_t)(row0 + lr) * FIN_ + lg * 8;
#pragma unroll
    for (int kk = 0; kk < FIN_; kk += 32) {
        float4 xa = *(const float4*)(xp + kk);
        float4 xb = *(const float4*)(xp + kk + 4);
        ABu af;
        af.s[0] = (short)f2b(xa.x); af.s[1] = (short)f2b(xa.y);
        af.s[2] = (short)f2b(xa.z); af.s[3] = (short)f2b(xa.w);
        af.s[4] = (short)f2b(xb.x); af.s[5] = (short)f2b(xb.y);
        af.s[6] = (short)f2b(xb.z); af.s[7] = (short)f2b(xb.w);
#pragma unroll
        for (int q = 0; q < 2; ++q) {
            ABu bf; bf.s = *(const vs8*)(WT + (fbase + q * 16 + lr) * FIN_ + kk + lg * 8);
            acc[q] = mfma16(af, bf, acc[q]);
        }
    }
    if (isH2) {
#pragma unroll
        for (int q = 0; q < 2; ++q)
#pragma unroll
            for (int r = 0; r < 4; ++r)
                h2[(size_t)(row0 + lg * 4 + r) * F_ + fbase + q * 16 + lr] = acc[q][r];
    }
#pragma unroll
    for (int q = 0; q < 2; ++q)
#pragma unroll
        for (int r = 0; r < 4; ++r)
            tb[lg * 4 + r][fbase + q * 16 + lr] = f2b(acc[q][r]);
    float a0 = av[fbase + lr], a1 = av[fbase + 16 + lr];
    float tv[4];
#pragma unroll
    for (int r = 0; r < 4; ++r) tv[r] = acc[0][r] * a0 + acc[1][r] * a1;
#pragma unroll
    for (int off = 1; off < 16; off <<= 1)
#pragma unroll
        for (int r = 0; r < 4; ++r) tv[r] += __shfl_xor(tv[r], off, 64);
    if ((l & 15) == 0)
#pragma unroll
        for (int r = 0; r < 4; ++r) sred[w][lg * 4 + r] = tv[r];
    __syncthreads();
    {
        int f = t >> 1, half = t & 1;
        vs8 o;
#pragma unroll
        for (int j = 0; j < 8; ++j) o[j] = (short)tb[half * 8 + j][f];
        *(vs8*)(HP + ((size_t)(row0 >> 5) * 128 + f) * 32 + (row0 & 16) + half * 8) = o;
    }
    if (t < 16) {
        float s = sred[0][t] + sred[1][t] + sred[2][t] + sred[3][t];
        sout[row0 + t] = s;
    }
}

// ---- FUSED: inter stats+bitmask | city/prov bitmask+counts | h2wP gather ----
__global__ __launch_bounds__(256) void k_adjgather(const int* __restrict__ inter, const float* __restrict__ s1,
                                                   const float* __restrict__ s2, unsigned short* __restrict__ bm,
                                                   float* __restrict__ rowmax, float* __restrict__ rowinv,
                                                   const int* __restrict__ city, const int* __restrict__ prov,
                                                   const int* __restrict__ src,
                                                   uint32_t* __restrict__ BMtc, uint32_t* __restrict__ BMtp,
                                                   float* __restrict__ w3, float* __restrict__ w4,
                                                   const float* __restrict__ h2, unsigned short* __restrict__ h2wP) {
    __shared__ float wred[8];
    int t = threadIdx.x;
    int wv = t >> 6, ln = t & 63;
    if (blockIdx.x < N_) {
        int n = blockIdx.x;
        const int* rp = inter + (size_t)n * M_ + t * 16;
        float sv[16]; unsigned mask = 0;
#pragma unroll
        for (int c = 0; c < 4; ++c) {
            int4 v = *(const int4*)(rp + c * 4);
            if (v.x > 0) mask |= 1u << (c * 4 + 0);
            if (v.y > 0) mask |= 1u << (c * 4 + 1);
            if (v.z > 0) mask |= 1u << (c * 4 + 2);
            if (v.w > 0) mask |= 1u << (c * 4 + 3);
            float4 s = *(const float4*)(s1 + t * 16 + c * 4);
            sv[c * 4 + 0] = s.x; sv[c * 4 + 1] = s.y; sv[c * 4 + 2] = s.z; sv[c * 4 + 3] = s.w;
        }
        bm[(size_t)n * 256 + t] = (unsigned short)(mask & 0xffffu);
        float mx = -3.0e38f;
#pragma unroll
        for (int j = 0; j < 16; ++j) if (mask & (1u << j)) mx = fmaxf(mx, sv[j]);
        for (int off = 32; off > 0; off >>= 1) mx = fmaxf(mx, __shfl_down(mx, off, 64));
        if (ln == 0) wred[wv] = mx;
        __syncthreads();
        float s1mx = fmaxf(fmaxf(wred[0], wred[1]), fmaxf(wred[2], wred[3]));
        float s2n = s2[n];
        float rmx = lrelu(s2n + s1mx);
        float sum = 0.f;
#pragma unroll
        for (int j = 0; j < 16; ++j) if (mask & (1u << j)) sum += __expf(lrelu(s2n + sv[j]) - rmx);
        for (int off = 32; off > 0; off >>= 1) sum += __shfl_down(sum, off, 64);
        if (ln == 0) wred[4 + wv] = sum;
        __syncthreads();
        if (t == 0) {
            float tot = wred[4] + wred[5] + wred[6] + wred[7];
            bool any = s1mx > -2.9e38f;
            rowmax[n] = any ? rmx : 0.f;
            rowinv[n] = (any && tot > 0.f) ? 1.0f / tot : 0.f;
        }
    } else if (blockIdx.x < N_ + 2 * B_) {
        int bb = blockIdx.x - N_;
        int b = bb & (B_ - 1);
        bool isC = bb < B_;
        const int* adj = isC ? city : prov;
        uint32_t* BM = isC ? BMtc : BMtp;
        float* wout = isC ? w3 : w4;
        const int* rowp = adj + (size_t)src[b] * N_;
        int cnt = 0;
#pragma unroll 4
        for (int i = 0; i < N_ / 256; ++i) {
            int v = rowp[i * 256 + t];
            unsigned long long bal = __ballot(v > 0);
            cnt += (v > 0);
            if (ln == 0) {
                int widx = i * 8 + wv * 2;
                BM[(size_t)widx * B_ + b] = (uint32_t)bal;
                BM[(size_t)(widx + 1) * B_ + b] = (uint32_t)(bal >> 32);
            }
        }
        float fc = (float)cnt;
        for (int off = 32; off > 0; off >>= 1) fc += __shfl_down(fc, off, 64);
        if (ln == 0) wred[wv] = fc;
        __syncthreads();
        if (t == 0) {
            float tot = wred[0] + wred[1] + wred[2] + wred[3];
            wout[b] = tot > 0.f ? 1.0f / tot : 0.f;
        }
    } else {
        int bblk = blockIdx.x - (N_ + 2 * B_);            // 64 blocks
        int f = t & 127, halfb = t >> 7;
        vs8 o0, o1;
#pragma unroll
        for (int i = 0; i < 8; ++i) {
            int b0 = bblk * 32 + halfb * 16 + i;
            o0[i] = (short)f2b(h2[(size_t)src[b0] * F_ + f]);
            int b1 = b0 + 8;
            o1[i] = (short)f2b(h2[(size_t)src[b1] * F_ + f]);
        }
        unsigned short* dst = h2wP + ((size_t)bblk * 128 + f) * 32 + halfb * 16;
        *(vs8*)dst = o0;
        *(vs8*)(dst + 8) = o1;
    }
}

// ---- materialize att: packed attP[mblk][n][m&31] AND transposed attT[nblk][m][n&31] ----
__global__ __launch_bounds__(256) void k_attmat2(const unsigned char* __restrict__ bm8,
                                                 const float* __restrict__ s1, const float* __restrict__ s2,
                                                 const float* __restrict__ rowmax, const float* __restrict__ rowinv,
                                                 unsigned short* __restrict__ attP,
                                                 unsigned short* __restrict__ attT) {
    __shared__ unsigned short tile[64][33];              // [m_local][n_local], padded
    int bx = blockIdx.x;                                 // 16384 = (M/64) x (N/32)
    int mt = bx & 63, nt = bx >> 6;
    int nb = nt * 32, mb = mt * 64;
    int t = threadIdx.x;
    int mo = t & 7, nl = t >> 3;                         // mo 0..7, nl 0..31
    int n = nb + nl;
    int m = mb + mo * 8;
    unsigned bits = bm8[(size_t)n * 512 + (m >> 3)];
    float s2n = s2[n], rmx = rowmax[n], rin = rowinv[n];
    float4 sa = *(const float4*)(s1 + m);
    float4 sb = *(const float4*)(s1 + m + 4);
    float sv[8] = {sa.x, sa.y, sa.z, sa.w, sb.x, sb.y, sb.z, sb.w};
    vs8 o;
#pragma unroll
    for (int j = 0; j < 8; ++j) {
        float v = (bits & (1u << j)) ? __expf(lrelu(s2n + sv[j]) - rmx) * rin : 0.f;
        o[j] = (short)f2b(v);
        tile[mo * 8 + j][nl] = (unsigned short)o[j];
    }
    *(vs8*)(attP + ((size_t)(m >> 5) * N_ + n) * 32 + (m & 31)) = o;
    __syncthreads();
    int mr = t >> 2, sg = t & 3;                         // mr 0..63, sg 0..3
    vs8 ot;
#pragma unroll
    for (int j = 0; j < 8; ++j) ot[j] = (short)tile[mr][sg * 8 + j];
    *(vs8*)(attT + ((size_t)nt * M_ + mb + mr) * 32 + sg * 8) = ot;
}

// ---- MERGED gemmA | gemmB (m97 geometry, glds16 dbuf) | gemmC — reduced K-splits ----
__global__ __launch_bounds__(256) void k_gemmABC(const unsigned short* __restrict__ attP,
                                                 const unsigned short* __restrict__ attT,
                                                 const unsigned short* __restrict__ h1P,
                                                 const unsigned short* __restrict__ h2P,
                                                 const uint32_t* __restrict__ BMtc, const uint32_t* __restrict__ BMtp,
                                                 const float* __restrict__ w3, const float* __restrict__ w4,
                                                 const unsigned short* __restrict__ h2wP,
                                                 float* __restrict__ uP, float* __restrict__ vP) {
    __shared__ __align__(16) unsigned short smem[16384];  // 32 KB: 2 buf x (A 8KB + B 8KB)
    int t = threadIdx.x;
    int w = t >> 6, l = t & 63;
    int lr = l & 15, lg = l >> 4;
    int bx = blockIdx.x;
    if (bx < 384) {
        // gemmA (bx<256): uP[y] = att @ h1 K-slice (64 x-tiles x 4 y, 32 steps)
        // gemmB (256..383): vP[y] = att.T @ h2 K-slice (32 x-tiles x 4 y, 64 steps)
        bool isA = bx < 256;
        int i = isA ? bx : bx - 256;
        int x, y, ns, kbase, rowsK;
        const unsigned short* Asrc; const unsigned short* Bsrc; float* Out;
        if (isA) { x = i & 63; y = i >> 6; ns = 32; kbase = y * 32; rowsK = N_;
                   Asrc = attP; Bsrc = h1P; Out = uP + (size_t)y * N_ * F_; }
        else     { x = i & 31; y = i >> 5; ns = 64; kbase = y * 64; rowsK = M_;
                   Asrc = attT; Bsrc = h2P; Out = vP + (size_t)y * M_ * F_; }
        int rb0 = x * 128;
        int rq = (w >> 1) * 64;                          // wave row-quadrant
        int cb = (w & 1) * 64;                           // wave col-half
        auto stage = [&](int kb, int buf) {
#pragma unroll
            for (int ii = 0; ii < 4; ++ii) {
                int c = w * 4 + ii;                      // 16 chunks of 1KB: 0-7 A, 8-15 B
                const unsigned short* g; int loff;
                if (c < 8) { g = Asrc + ((size_t)kb * rowsK + rb0) * 32 + c * 512 + l * 8;
                             loff = buf * 8192 + c * 512; }
                else       { g = Bsrc + (size_t)kb * 4096 + (c - 8) * 512 + l * 8;
                             loff = buf * 8192 + 4096 + (c - 8) * 512; }
                glds16(g, smem + loff);
            }
        };
        vf4 acc[4][4] = {};
        stage(kbase, 0);
        __syncthreads();
        int cur = 0;
        for (int step = 0; step < ns; ++step) {
            if (step + 1 < ns) stage(kbase + step + 1, cur ^ 1);
            const unsigned short* base = smem + cur * 8192;
            ABu a[4], b[4];
#pragma unroll
            for (int s = 0; s < 4; ++s) a[s].s = *(const vs8*)(base + (rq + s * 16 + lr) * 32 + lg * 8);
#pragma unroll
            for (int q = 0; q < 4; ++q) b[q].s = *(const vs8*)(base + 4096 + (cb + q * 16 + lr) * 32 + lg * 8);
#pragma unroll
            for (int s = 0; s < 4; ++s)
#pragma unroll
                for (int q = 0; q < 4; ++q) acc[s][q] = mfma16(a[s], b[q], acc[s][q]);
            __syncthreads();                             // reads done + stage vmcnt drained
            cur ^= 1;
        }
#pragma unroll
        for (int s = 0; s < 4; ++s)
#pragma unroll
            for (int q = 0; q < 4; ++q)
#pragma unroll
                for (int r = 0; r < 4; ++r)
                    Out[(size_t)(rb0 + rq + s * 16 + lg * 4 + r) * F_ + cb + q * 16 + lr] = acc[s][q][r];
    } else {
        // ---- gemmC: uP[4+y] = G @ h2w K-slice (128 x-tiles x 2 y) ----
        int i = bx - 384;
        int xc = i & 127, yc = i >> 7;                   // 128 x 2
        int nb0 = xc * 64 + (w & 1) * 32;                // 32-aligned -> wi uniform per wave
        int fb = (w >> 1) * 64;
        int wi = nb0 >> 5;
        const uint32_t* bc = BMtc + (size_t)wi * B_;
        const uint32_t* bp = BMtp + (size_t)wi * B_;
        vf4 acc[2][4] = {};
        int b0s = yc * (B_ / 2);
        for (int b0 = b0s; b0 < b0s + B_ / 2; b0 += 32) {
            int bb = b0 + lg * 8;
            uint4 c0 = *(const uint4*)(bc + bb);
            uint4 c1 = *(const uint4*)(bc + bb + 4);
            uint4 p0 = *(const uint4*)(bp + bb);
            uint4 p1 = *(const uint4*)(bp + bb + 4);
            float4 wa = *(const float4*)(w3 + bb);
            float4 wb = *(const float4*)(w3 + bb + 4);
            float4 wc = *(const float4*)(w4 + bb);
            float4 wd = *(const float4*)(w4 + bb + 4);
            const unsigned short* hb = h2wP + (size_t)(b0 >> 5) * 128 * 32;
            ABu bf0, bf1, bf2, bf3;
            bf0.s = *(const vs8*)(hb + (size_t)(fb + lr) * 32 + lg * 8);
            bf1.s = *(const vs8*)(hb + (size_t)(fb + 16 + lr) * 32 + lg * 8);
            bf2.s = *(const vs8*)(hb + (size_t)(fb + 32 + lr) * 32 + lg * 8);
            bf3.s = *(const vs8*)(hb + (size_t)(fb + 48 + lr) * 32 + lg * 8);
            uint32_t cw[8] = {c0.x, c0.y, c0.z, c0.w, c1.x, c1.y, c1.z, c1.w};
            uint32_t pw[8] = {p0.x, p0.y, p0.z, p0.w, p1.x, p1.y, p1.z, p1.w};
            float w3v[8] = {wa.x, wa.y, wa.z, wa.w, wb.x, wb.y, wb.z, wb.w};
            float w4v[8] = {wc.x, wc.y, wc.z, wc.w, wd.x, wd.y, wd.z, wd.w};
            ABu af0, af1;
#pragma unroll
            for (int j = 0; j < 8; ++j) {
                float v0 = (((cw[j] >> lr) & 1u) ? w3v[j] : 0.f) + (((pw[j] >> lr) & 1u) ? w4v[j] : 0.f);
                float v1 = (((cw[j] >> (16 + lr)) & 1u) ? w3v[j] : 0.f) + (((pw[j] >> (16 + lr)) & 1u) ? w4v[j] : 0.f);
                af0.s[j] = (short)f2b(v0);
                af1.s[j] = (short)f2b(v1);
            }
            acc[0][0] = mfma16(af0, bf0, acc[0][0]);
            acc[1][0] = mfma16(af1, bf0, acc[1][0]);
            acc[0][1] = mfma16(af0, bf1, acc[0][1]);
            acc[1][1] = mfma16(af1, bf1, acc[1][1]);
            acc[0][2] = mfma16(af0, bf2, acc[0][2]);
            acc[1][2] = mfma16(af1, bf2, acc[1][2]);
            acc[0][3] = mfma16(af0, bf3, acc[0][3]);
            acc[1][3] = mfma16(af1, bf3, acc[1][3]);
        }
        float* Out = uP + (size_t)(4 + yc) * N_ * F_;
#pragma unroll
        for (int s = 0; s < 2; ++s)
#pragma unroll
            for (int q = 0; q < 4; ++q)
#pragma unroll
                for (int r = 0; r < 4; ++r)
                    Out[(size_t)(nb0 + s * 16 + lg * 4 + r) * F_ + fb + q * 16 + lr] = acc[s][q][r];
    }
}

// ---- batchnorm column stats straight from partial slabs (no u_in/v_in materialize) ----
__global__ __launch_bounds__(256) void k_bnstats3(const float* __restrict__ vP, const float* __restrict__ uP,
                                                  float* __restrict__ stats) {
    __shared__ float r1[256], r2[256];
    int bx = blockIdx.x;
    int f = threadIdx.x & 127;
    int half = threadIdx.x >> 7;
    float s = 0.f, s2v = 0.f;
    if (bx < 256) {
        size_t stride = (size_t)M_ * F_;
        for (int r = bx * 2 + half; r < M_; r += 512) {
            float v = 0.f;
#pragma unroll
            for (int y = 0; y < 4; ++y) v += vP[(size_t)y * stride + (size_t)r * F_ + f];
            s += v; s2v += v * v;
        }
        r1[threadIdx.x] = s; r2[threadIdx.x] = s2v;
        __syncthreads();
        if (half == 0) {
            atomicAdd(&stats[f], r1[f] + r1[f + 128]);
            atomicAdd(&stats[128 + f], r2[f] + r2[f + 128]);
        }
    } else {
        int b = bx - 256;
        size_t stride = (size_t)N_ * F_;
        for (int r = b * 2 + half; r < N_; r += 512) {
            float v = 0.f;
#pragma unroll
            for (int y = 0; y < 6; ++y) v += uP[(size_t)y * stride + (size_t)r * F_ + f];
            s += v; s2v += v * v;
        }
        r1[threadIdx.x] = s; r2[threadIdx.x] = s2v;
        __syncthreads();
        if (half == 0) {
            atomicAdd(&stats[256 + f], r1[f] + r1[f + 128]);
            atomicAdd(&stats[384 + f], r2[f] + r2[f + 128]);
        }
    }
}

// ---- bn finalize + sum partials in-register + apply + leaky + cast bf16 ----
__global__ __launch_bounds__(256) void k_bnapplyP(const float* __restrict__ vP, const float* __restrict__ uP,
                                                  const float* __restrict__ stats,
                                                  const float* __restrict__ g1, const float* __restrict__ b1,
                                                  const float* __restrict__ g2, const float* __restrict__ b2,
                                                  unsigned short* __restrict__ v_outb, unsigned short* __restrict__ u_outb) {
    __shared__ float sc[256], sh[256];                    // [which*128+f]
    int t = threadIdx.x;
    {
        int which = t >> 7, f = t & 127;
        const float* sum = stats + which * 256;
        const float* sq = sum + 128;
        const float* g = which ? g2 : g1;
        const float* be = which ? b2 : b1;
        float R = which ? (float)N_ : (float)M_;
        float mean = sum[f] / R;
        float var = sq[f] / R - mean * mean;
        float s = g[f] * rsqrtf(var + 1e-5f);
        sc[t] = s; sh[t] = be[f] - mean * s;
    }
    __syncthreads();
    int id4 = blockIdx.x * 256 + t;                       // one float4 per thread
    int idx = id4 * 4;
    int which = idx >= M_ * F_;
    int rel = which ? idx - M_ * F_ : idx;
    int f0 = (rel & 127) + which * 128;
    float4 p = make_float4(0.f, 0.f, 0.f, 0.f);
    unsigned short* Q;
    if (!which) {
        size_t stride = (size_t)M_ * F_;
#pragma unroll
        for (int y = 0; y < 4; ++y) {
            float4 q = *(const float4*)(vP + (size_t)y * stride + rel);
            p.x += q.x; p.y += q.y; p.z += q.z; p.w += q.w;
        }
        Q = v_outb;
    } else {
        size_t stride = (size_t)N_ * F_;
#pragma unroll
        for (int y = 0; y < 6; ++y) {
            float4 q = *(const float4*)(uP + (size_t)y * stride + rel);
            p.x += q.x; p.y += q.y; p.z += q.z; p.w += q.w;
        }
        Q = u_outb;
    }
    ushort4 o;
    o.x = f2b(lrelu(p.x * sc[f0 + 0] + sh[f0 + 0]));
    o.y = f2b(lrelu(p.y * sc[f0 + 1] + sh[f0 + 1]));
    o.z = f2b(lrelu(p.z * sc[f0 + 2] + sh[f0 + 2]));
    o.w = f2b(lrelu(p.w * sc[f0 + 3] + sh[f0 + 3]));
    *(ushort4*)(Q + rel) = o;
}

// ---------------- out = elu(U @ V^T) ----------------
__global__ __launch_bounds__(256) void k_gemmD(const unsigned short* __restrict__ U,
                                               const unsigned short* __restrict__ V,
                                               float* __restrict__ out) {
    int w = threadIdx.x >> 6, l = threadIdx.x & 63;
    int lr = l & 15, lg = l >> 4;
    int nb = blockIdx.x * 64 + w * 16;
    int mb = blockIdx.y * 64;
    vf4 acc[4] = {};
#pragma unroll
    for (int k0 = 0; k0 < F_; k0 += 32) {
        ABu af; af.s = *(const vs8*)(U + (size_t)(nb + lr) * F_ + k0 + lg * 8);
#pragma unroll
        for (int q = 0; q < 4; ++q) {
            ABu bf; bf.s = *(const vs8*)(V + (size_t)(mb + q * 16 + lr) * F_ + k0 + lg * 8);
            acc[q] = mfma16(af, bf, acc[q]);
        }
    }
#pragma unroll
    for (int q = 0; q < 4; ++q)
#pragma unroll
        for (int r = 0; r < 4; ++r) {
            int row = nb + lg * 4 + r;
            int col = mb + q * 16 + lr;
            float x = acc[q][r];
            out[(size_t)row * M_ + col] = x > 0.f ? x : __expf(x) - 1.f;
        }
}

extern "C" void kernel_launch(void* const* d_in, const int* in_sizes, int n_in,
                              void* d_out, int out_size, void* d_ws, size_t ws_size,
                              hipStream_t stream) {
    const float* Sinput = (const float*)d_in[0];
    const float* Rinput = (const float*)d_in[1];
    const int* inter_adj = (const int*)d_in[2];
    const int* city_adj = (const int*)d_in[3];
    const int* prov_adj = (const int*)d_in[4];
    const int* src = (const int*)d_in[5];
    const float* W1 = (const float*)d_in[6];
    const float* W2 = (const float*)d_in[7];
    const float* a = (const float*)d_in[8];
    const float* g1 = (const float*)d_in[11];
    const float* b1 = (const float*)d_in[12];
    const float* g2 = (const float*)d_in[13];
    const float* b2 = (const float*)d_in[14];
    float* out = (float*)d_out;

    char* ws = (char*)d_ws;
    size_t o = 0;
    auto take = [&](size_t bytes) { char* p = ws + o; o += (bytes + 255) & ~(size_t)255; return p; };
    float* stats = (float*)take(512 * 4);
    size_t zero_bytes = o;                               // ONLY stats zeroed
    float* uP = (float*)take((size_t)6 * N_ * F_ * 4);   // 24 MB: gemmA y0..3 + gemmC y4..5
    float* vP = (float*)take((size_t)4 * M_ * F_ * 4);   // 8 MB: gemmB y0..3
    float* h2 = (float*)take((size_t)N_ * F_ * 4);
    unsigned short* h1P = (unsigned short*)take((size_t)(M_ / 32) * 128 * 32 * 2);
    unsigned short* h2P = (unsigned short*)take((size_t)(N_ / 32) * 128 * 32 * 2);
    unsigned short* W1T = (unsigned short*)take((size_t)F_ * FIN_ * 2);
    unsigned short* W2T = (unsigned short*)take((size_t)F_ * FIN_ * 2);
    float* s1 = (float*)take(M_ * 4);
    float* s2 = (float*)take(N_ * 4);
    float* rowmax = (float*)take(N_ * 4);
    float* rowinv = (float*)take(N_ * 4);
    float* w3 = (float*)take(B_ * 4);
    float* w4 = (float*)take(B_ * 4);
    unsigned short* h2wP = (unsigned short*)take((size_t)(B_ / 32) * 128 * 32 * 2);
    unsigned short* u_outb = (unsigned short*)take((size_t)N_ * F_ * 2);
    unsigned short* v_outb = (unsigned short*)take((size_t)M_ * F_ * 2);
    uint32_t* BMtc = (uint32_t*)take((size_t)256 * B_ * 4);
    uint32_t* BMtp = (uint32_t*)take((size_t)256 * B_ * 4);
    unsigned short* bm = (unsigned short*)take((size_t)N_ * 256 * 2);      // 4 MB, [n][m-bits]
    unsigned short* attP = (unsigned short*)take((size_t)N_ * M_ * 2);     // 64 MB packed
    unsigned short* attT = (unsigned short*)take((size_t)N_ * M_ * 2);     // 64 MB transposed-packed
    (void)ws_size; (void)in_sizes; (void)n_in; (void)out_size;

    int nz4 = (int)(zero_bytes / 16);
    int zblocks = (nz4 + 255) / 256;
    k_prep<<<256 + zblocks, 256, 0, stream>>>(W1, W2, W1T, W2T, (float4*)d_ws, nz4);
    k_hgemmF<<<(M_ + N_) / 16, 256, 0, stream>>>(Rinput, Sinput, W1T, W2T, a, h2, h1P, h2P, s1, s2);
    k_adjgather<<<N_ + 2 * B_ + B_ / 32, 256, 0, stream>>>(inter_adj, s1, s2, bm, rowmax, rowinv,
                                                           city_adj, prov_adj, src, BMtc, BMtp, w3, w4,
                                                           h2, h2wP);
    k_attmat2<<<16384, 256, 0, stream>>>((const unsigned char*)bm, s1, s2, rowmax, rowinv, attP, attT);
    k_gemmABC<<<640, 256, 0, stream>>>(attP, attT, h1P, h2P, BMtc, BMtp, w3, w4, h2wP, uP, vP);
    k_bnstats3<<<512, 256, 0, stream>>>(vP, uP, stats);
    k_bnapplyP<<<(M_ + N_) * F_ / 4 / 256, 256, 0, stream>>>(vP, uP, stats, g1, b1, g2, b2, v_outb, u_outb);
    k_gemmD<<<dim3(N_ / 64, M_ / 64), 256, 0, stream>>>(u_outb, v_outb, out);
}